// Round 9
// baseline (425.142 us; speedup 1.0000x reference)
//
#include <hip/hip_runtime.h>
#include <stdint.h>

// out[(b,m),n] = (sum_k x_q[(b,m),k] * w[n,k]) * sx[(b,m)] * ws[n] + bias[n]
// pass 1: int32 -> packed int8, two one-shot launches (R0 style).
// pass 2: 256x256-tile i8 GEMM on mfma_i32_32x32x32 (4404 TOPS ceiling vs
//         3944 for 16x16x64), 8 waves of 128x64 wave tiles, 4-deep 128KB LDS
//         ring, counted vmcnt(8) (never drains in-loop), one s_barrier per
//         K-tile, setprio around MFMA clusters — R1/R7's proven skeleton.
//         NEW: interleaved LDS layout (row-group 32 x [chunk][row][16B],
//         addr=(row>>5)*2048+chunk*512+(row&31)*16) realized by per-lane
//         global source permutation (LDS dest stays linear for gload_lds).
//         Fragment reads become linear 16B bursts across 16 lanes -> fixes
//         R4's 4cy/read bank conflict (12.6M cycles) that sank the 32x32
//         shape. Epilogue = R4's harness-verified 32x32 C/D map.
//         History: R1/R7 136.8us best; R2 -5; R4 -10 (conflicts); R5 -23;
//         R6 -4; R8 -19 (2blk/CU anti-phase refuted).
#define MROWS 8192
#define K_DIM 4096
#define N_DIM 4096
#define BM 256
#define BN 256
#define BK 64                 // bytes of K per tile
#define KT (K_DIM / BK)       // 64 K-tiles
#define ABYTES (BM * BK)      // 16 KB per matrix per tile
#define TBYTES (2 * ABYTES)   // 32 KB per ring slot (A+B)

#define X_ELEMS (MROWS * K_DIM)
#define W_ELEMS (N_DIM * K_DIM)

typedef __attribute__((ext_vector_type(4)))  int   int4v;
typedef __attribute__((ext_vector_type(16))) int   int16v;
typedef __attribute__((ext_vector_type(4)))  float float4v;

#define GLOAD_LDS16(gptr, lptr)                                                   \
    __builtin_amdgcn_global_load_lds((const __attribute__((address_space(1))) void*)(gptr), \
                                     (__attribute__((address_space(3))) void*)(lptr), 16, 0, 0)

// ---- pass 1: int32 -> packed int8, 16 elems (64 B read -> 16 B write) / lane --
__device__ __forceinline__ int pack4(int4v v) {
    return (int)((unsigned)(v[0] & 0xFF)
               | ((unsigned)(v[1] & 0xFF) << 8)
               | ((unsigned)(v[2] & 0xFF) << 16)
               | ((unsigned)(v[3] & 0xFF) << 24));
}

__global__ __launch_bounds__(256) void pack_i32_to_i8(
    const int4v* __restrict__ src, int4v* __restrict__ dst, int n16)
{
    int i = blockIdx.x * blockDim.x + threadIdx.x;
    if (i >= n16) return;
    int4v a = src[4 * i + 0];
    int4v b = src[4 * i + 1];
    int4v c = src[4 * i + 2];
    int4v d = src[4 * i + 3];
    int4v r;
    r[0] = pack4(a); r[1] = pack4(b); r[2] = pack4(c); r[3] = pack4(d);
    dst[i] = r;
}

// ---- pass 2: i8 GEMM + dequant epilogue -------------------------------------
// LDS layout per matrix tile (16 KB): 8 row-groups of 32 rows; group g at
// g*2048; within group: chunk c (16B of k) at c*512; row r&31 at (r&31)*16.
// Staging wave w covers group w: gload_lds #1 writes chunks {0,1} (lane l ->
// chunk l>>5, row l&31), #2 writes chunks {2,3}; the per-lane GLOBAL address
// encodes (row, chunk) so the linear LDS placement lands the layout.
// 32x32x32 fragment read: lane l reads chunk 2s+(l>>5), row l&31 -> byte
// (2s+hi)*512 + m32*16 : 16 consecutive lanes = 16 consecutive 16B slots.
__global__ __launch_bounds__(512, 2) void i8gemm_dq_kernel(
    const int8_t* __restrict__ xq,   // (8192, 4096) packed i8
    const float*  __restrict__ sx,   // (8192,)
    const int8_t* __restrict__ wt,   // (4096, 4096) packed i8 (row = n)
    const float*  __restrict__ ws,   // (4096,)
    const float*  __restrict__ bias, // (4096,)
    float*        __restrict__ out)  // (8192, 4096) f32
{
    __shared__ __align__(16) int8_t lds8[4 * TBYTES];   // 128 KB ring

    const int tid  = threadIdx.x;
    const int wave = tid >> 6;
    const int lane = tid & 63;
    const int wr   = wave >> 2;   // 0..1 : 128-row half of the 256-row tile
    const int wcn  = wave & 3;    // 0..3 : 64-col quarter of the 256-col tile

    // XCD-aware swizzle: 512 blocks, 8 XCDs, 64 contiguous wgs per XCD
    const int bid = blockIdx.x;
    const int wg  = (bid & 7) * 64 + (bid >> 3);
    const int ct  = wg & 15;          // 16 col tiles
    const int rt  = wg >> 4;          // 32 row tiles

    // ---- staging addressing: wave w stages row-group w (rows 32w..32w+31)
    // of A and of B. Lane l -> row l&31, k-chunk l>>5 (call #2 adds +32B).
    const int sr = lane & 31;
    const int sc = (lane >> 5) * 16;
    const int8_t* gA = xq + (size_t)(rt * BM + wave * 32 + sr) * K_DIM + sc;
    const int8_t* gB = wt + (size_t)(ct * BN + wave * 32 + sr) * K_DIM + sc;
    const int dA = wave * 2048;            // LDS dest offsets (wave-uniform)
    const int dB = ABYTES + wave * 2048;

    // ---- fragment read addressing (interleaved layout, linear bursts) ----
    const int m32  = lane & 31;
    const int hi   = lane >> 5;
    const int rb   = hi * 512 + m32 * 16;           // + s*1024 selects k-slice
    const int aoff = (wr * 4) * 2048 + rb;          // + i*2048
    const int boff = ABYTES + (wcn * 2) * 2048 + rb;// + j*2048

    int16v acc[4][2] = {};   // 4x2 of 32x32 int32 accumulators per wave

#define STAGE_A(U, BB) { const size_t ko_ = (size_t)(U) * BK;   \
        GLOAD_LDS16(gA + ko_,      (BB) + dA);                  \
        GLOAD_LDS16(gA + ko_ + 32, (BB) + dA + 1024); }
#define STAGE_B(U, BB) { const size_t ko_ = (size_t)(U) * BK;   \
        GLOAD_LDS16(gB + ko_,      (BB) + dB);                  \
        GLOAD_LDS16(gB + ko_ + 32, (BB) + dB + 1024); }

    // prologue: stage tiles 0..2 into slots 0..2 -> 12 loads/wave in flight
    #pragma unroll
    for (int u = 0; u < 3; ++u) {
        int8_t* bb = lds8 + u * TBYTES;
        STAGE_A(u, bb);
        STAGE_B(u, bb);
    }

    #pragma unroll 4
    for (int t = 0; t < KT; ++t) {
        const int  buf = t & 3;
        const int  nb  = (t + 3) & 3;           // ring slot last read at t-1: dead
        const int  u   = (t + 3) & (KT - 1);    // wraps at the tail (data unused)
        const int8_t* base = lds8 + buf * TBYTES;
        int8_t* nbb = lds8 + nb * TBYTES;

        // land this tile's 4 loads (oldest), keep 8 in flight; then barrier so
        // every wave's staging of this tile is visible to every other wave.
        asm volatile("s_waitcnt vmcnt(8)" ::: "memory");
        __builtin_amdgcn_s_barrier();
        __builtin_amdgcn_sched_barrier(0);

        // phase 0: m-tiles 0,1 (rows wr*128 + 0..63), both k-slices; B all
        int4v a0[2][2], bf[2][2];
        #pragma unroll
        for (int i = 0; i < 2; ++i)
            #pragma unroll
            for (int s = 0; s < 2; ++s)
                a0[i][s] = *(const int4v*)(base + aoff + i * 2048 + s * 1024);
        #pragma unroll
        for (int j = 0; j < 2; ++j)
            #pragma unroll
            for (int s = 0; s < 2; ++s)
                bf[j][s] = *(const int4v*)(base + boff + j * 2048 + s * 1024);
        STAGE_A(u, nbb);   // prefetch A of tile t+3

        __builtin_amdgcn_s_setprio(1);
        #pragma unroll
        for (int s = 0; s < 2; ++s)
            #pragma unroll
            for (int i = 0; i < 2; ++i)
                #pragma unroll
                for (int j = 0; j < 2; ++j)
                    acc[i][j] = __builtin_amdgcn_mfma_i32_32x32x32_i8(
                                    a0[i][s], bf[j][s], acc[i][j], 0, 0, 0);
        __builtin_amdgcn_s_setprio(0);

        // phase 1: m-tiles 2,3 (rows wr*128 + 64..127), B frags reused
        int4v a1[2][2];
        #pragma unroll
        for (int i = 0; i < 2; ++i)
            #pragma unroll
            for (int s = 0; s < 2; ++s)
                a1[i][s] = *(const int4v*)(base + aoff + (2 + i) * 2048 + s * 1024);
        STAGE_B(u, nbb);   // prefetch B of tile t+3

        __builtin_amdgcn_s_setprio(1);
        #pragma unroll
        for (int s = 0; s < 2; ++s)
            #pragma unroll
            for (int i = 0; i < 2; ++i)
                #pragma unroll
                for (int j = 0; j < 2; ++j)
                    acc[2 + i][j] = __builtin_amdgcn_mfma_i32_32x32x32_i8(
                                        a1[i][s], bf[j][s], acc[2 + i][j], 0, 0, 0);
        __builtin_amdgcn_s_setprio(0);
    }

#undef STAGE_A
#undef STAGE_B

    // drain LDS-DMA before workgroup can end (ring slots die with the WG)
    asm volatile("s_waitcnt vmcnt(0)" ::: "memory");

    // ---- epilogue (R4 harness-verified): 32x32 C/D layout
    // col = lane&31, row = (reg&3) + 8*(reg>>2) + 4*(lane>>5)
    const int row_base = rt * BM + wr * 128;
    const int col_base = ct * BN + wcn * 64;

    float wsc[2], bsc[2];
    #pragma unroll
    for (int j = 0; j < 2; ++j) {
        const int c = col_base + j * 32 + m32;
        wsc[j] = ws[c];
        bsc[j] = bias[c];
    }

    #pragma unroll
    for (int i = 0; i < 4; ++i) {
        #pragma unroll
        for (int q = 0; q < 4; ++q) {          // register quad -> 4 consecutive rows
            const int r0 = row_base + i * 32 + q * 8 + hi * 4;
            const float4v sx4 = *(const float4v*)(sx + r0);
            #pragma unroll
            for (int j = 0; j < 2; ++j) {
                const int c = col_base + j * 32 + m32;
                float* o = out + (size_t)r0 * N_DIM + c;
                #pragma unroll
                for (int r = 0; r < 4; ++r)
                    o[(size_t)r * N_DIM] = (float)acc[i][j][q * 4 + r] * sx4[r] * wsc[j] + bsc[j];
            }
        }
    }
}

extern "C" void kernel_launch(void* const* d_in, const int* in_sizes, int n_in,
                              void* d_out, int out_size, void* d_ws, size_t ws_size,
                              hipStream_t stream) {
    const int*   xq32 = (const int*)d_in[0];
    const float* sx   = (const float*)d_in[1];
    const int*   wt32 = (const int*)d_in[2];
    const float* ws   = (const float*)d_in[3];
    const float* bias = (const float*)d_in[4];
    float* out = (float*)d_out;

    int8_t* xq8 = (int8_t*)d_ws;
    int8_t* wt8 = xq8 + (size_t)X_ELEMS;

    {
        int n16x = X_ELEMS / 16;
        int n16w = W_ELEMS / 16;
        pack_i32_to_i8<<<n16x / 256, 256, 0, stream>>>((const int4v*)xq32, (int4v*)xq8, n16x);
        pack_i32_to_i8<<<n16w / 256, 256, 0, stream>>>((const int4v*)wt32, (int4v*)wt8, n16w);
    }

    dim3 grid((MROWS / BM) * (N_DIM / BN));  // 512 blocks
    i8gemm_dq_kernel<<<grid, 512, 0, stream>>>(xq8, sx, wt8, ws, bias, out);
}